// Round 7
// baseline (319.659 us; speedup 1.0000x reference)
//
#include <hip/hip_runtime.h>
#include <stdint.h>

typedef __attribute__((ext_vector_type(8))) __bf16 bf16x8;
typedef __attribute__((ext_vector_type(4))) float f32x4;
typedef uint16_t u16;
typedef __attribute__((address_space(1))) uint32_t ga_u32;
typedef __attribute__((address_space(3))) uint32_t lds_u32;

#define MFMA16(a, b, c) __builtin_amdgcn_mfma_f32_16x16x32_bf16(a, b, c, 0, 0, 0)

static __device__ __forceinline__ u16 f2bf(float f) {
  uint32_t u = __float_as_uint(f);
  u += 0x7FFFu + ((u >> 16) & 1u);  // round-to-nearest-even
  return (u16)(u >> 16);
}

static __device__ __forceinline__ void async_cp16(const void* src, void* dst) {
  // global -> LDS direct copy, 16 B per lane; LDS dst is wave-uniform base + lane*16.
  __builtin_amdgcn_global_load_lds((ga_u32*)src, (lds_u32*)dst, 16, 0, 0);
}

// ---------------- fp32 -> bf16 cast (vectorized) ----------------
__global__ void cast_bf16_kernel(const float* __restrict__ in, u16* __restrict__ out, int n4) {
  int i = blockIdx.x * 256 + threadIdx.x;
  if (i < n4) {
    float4 v = reinterpret_cast<const float4*>(in)[i];
    ushort4 o;
    o.x = f2bf(v.x); o.y = f2bf(v.y); o.z = f2bf(v.z); o.w = f2bf(v.w);
    reinterpret_cast<ushort4*>(out)[i] = o;
  }
}

// ---------------- transpose + cast: W[K][N] fp32 -> WT[N][K] bf16 ----------------
__global__ void transpose_cast_kernel(const float* __restrict__ W, u16* __restrict__ WT,
                                      int K, int N) {
  __shared__ float tile[32][33];
  int tx = threadIdx.x & 31, ty = threadIdx.x >> 5;  // 32 x 8
  int n0 = blockIdx.x * 32, k0 = blockIdx.y * 32;
#pragma unroll
  for (int i = 0; i < 32; i += 8)
    tile[ty + i][tx] = W[(size_t)(k0 + ty + i) * N + n0 + tx];
  __syncthreads();
#pragma unroll
  for (int i = 0; i < 32; i += 8)
    WT[(size_t)(n0 + ty + i) * K + k0 + tx] = f2bf(tile[tx][ty + i]);
}

// ---------------- bf16 GEMM: C[M][N] = A[M][K] @ BT[N][K]^T + bias ----------------
// 256x128 tile, BK=32, 8 waves (4x2 of 64x64), double-buffered global_load_lds.
// 1D grid with XCD-aware bijective swizzle (nwg % 8 == 0 for both launches).
// LDS XOR swizzle: 16B slot s of row r holds global slot s ^ ((r>>1)&3)  (2-way reads).
// MODE 0: f32 out (stride OUTN). MODE 1: bf16 out for col<2560 (stride OUTN) + V cols
//         (>=2560) written transposed to vT[(b*8+g)*64 + d][2048].
template <int MODE>
__global__ __launch_bounds__(512)
void gemm_bt_kernel(const u16* __restrict__ A, const u16* __restrict__ BT,
                    const float* __restrict__ bias, void* __restrict__ C,
                    u16* __restrict__ vT,
                    int NBX, int N, int K, int OUTN) {
  __shared__ __align__(16) u16 sA[2][256 * 32];
  __shared__ __align__(16) u16 sB[2][128 * 32];
  int tid = threadIdx.x, lane = tid & 63, wave = tid >> 6;  // 0..7
  int wm = wave >> 1, wn = wave & 1;                        // 4 x 2
  int nwg = gridDim.x, wid = blockIdx.x;
  int swz = (wid & 7) * (nwg >> 3) + (wid >> 3);   // XCD-contiguous remap
  int by = swz / NBX, bx = swz - by * NBX;
  int row0 = by * 256, col0 = bx * 128;
  int l15 = lane & 15, l4 = lane >> 4;

  int srowA = wave * 32 + (lane >> 2);                      // j adds 16 (same swz: 16>>1 % 4 == 0)
  int sslotA = (((lane & 3) ^ ((srowA >> 1) & 3))) * 8;
  int srowB = wave * 16 + (lane >> 2);
  int sslotB = (((lane & 3) ^ ((srowB >> 1) & 3))) * 8;

  auto stage = [&](int k0, int buf) {
#pragma unroll
    for (int j = 0; j < 2; ++j)
      async_cp16(A + (size_t)(row0 + srowA + j * 16) * K + k0 + sslotA,
                 &sA[buf][(wave * 2 + j) * 512]);
    async_cp16(BT + (size_t)(col0 + srowB) * K + k0 + sslotB, &sB[buf][wave * 512]);
  };

  f32x4 acc[4][4] = {};
  stage(0, 0);
  __syncthreads();
  int nk = K >> 5, cur = 0;
  for (int kt = 0; kt < nk; ++kt) {
    if (kt + 1 < nk) stage((kt + 1) * 32, cur ^ 1);
    bf16x8 af[4], bfr[4];
#pragma unroll
    for (int m = 0; m < 4; ++m) {
      int ra = wm * 64 + m * 16 + l15;
      af[m] = *reinterpret_cast<const bf16x8*>(&sA[cur][ra * 32 + ((l4 ^ ((ra >> 1) & 3)) & 3) * 8]);
    }
#pragma unroll
    for (int n = 0; n < 4; ++n) {
      int rb = wn * 64 + n * 16 + l15;
      bfr[n] = *reinterpret_cast<const bf16x8*>(&sB[cur][rb * 32 + ((l4 ^ ((rb >> 1) & 3)) & 3) * 8]);
    }
#pragma unroll
    for (int m = 0; m < 4; ++m)
#pragma unroll
      for (int n = 0; n < 4; ++n)
        acc[m][n] = MFMA16(af[m], bfr[n], acc[m][n]);
    __syncthreads();  // drains vmcnt (staging) + lgkmcnt (frag reads)
    cur ^= 1;
  }

  bool vpart = (MODE == 1) && (col0 >= 2560);  // block-uniform (col0 128-aligned)
#pragma unroll
  for (int m = 0; m < 4; ++m) {
#pragma unroll
    for (int n = 0; n < 4; ++n) {
      int col = col0 + wn * 64 + n * 16 + l15;
      float bv = bias[col];
      int rowb = row0 + wm * 64 + m * 16 + l4 * 4;
      if (vpart) {
        int hk = (col - 2560) >> 6, d = col & 63;
        int b = rowb >> 11, s = rowb & 2047;
        ushort4 o;
        o.x = f2bf(acc[m][n][0] + bv); o.y = f2bf(acc[m][n][1] + bv);
        o.z = f2bf(acc[m][n][2] + bv); o.w = f2bf(acc[m][n][3] + bv);
        *reinterpret_cast<ushort4*>(&vT[((size_t)((b * 8 + hk) * 64 + d)) * 2048 + s]) = o;
      } else {
#pragma unroll
        for (int e = 0; e < 4; ++e) {
          float v = acc[m][n][e] + bv;
          if (MODE == 1)
            ((u16*)C)[(size_t)(rowb + e) * OUTN + col] = f2bf(v);
          else
            ((float*)C)[(size_t)(rowb + e) * OUTN + col] = v;
        }
      }
    }
  }
}

// ---------------- GQA flash attention (swapped QK^T, no-max exp2, MFMA row-sums) ----
// 1D grid 512 (XCD-swizzled), 256 thr = 4 waves, BQ=256 (64 q/wave), BKV=64, D=64.
// Swapped QK^T (mfma(K,Q)): lane owns q=l15, keys l4*4+e -> vectorized b64 P-writes.
// K/V frag reads amortized over 64 q-rows/wave (LDS traffic/work -33% vs BQ=128).
// Pw: per-wave 64q x 64key bf16, 128B rows XOR-swizzled (byte ^= (row&7)<<4).
// LDS = 16K + 16K + 32K = 64KB -> 2 blocks/CU (exactly 1 residency pass, 512 wg).
__global__ __launch_bounds__(256, 2)
void attn_kernel(const u16* __restrict__ qkv, const u16* __restrict__ vTg,
                 u16* __restrict__ attno) {
  __shared__ __align__(16) u16 Kl[2][64 * 64];
  __shared__ __align__(16) u16 Vl[2][64 * 64];
  __shared__ __align__(16) u16 Pw[4][64 * 64];

  int wid = blockIdx.x;
  int swz = (wid & 7) * 64 + (wid >> 3);   // 512 wg: 64 per XCD, qt fastest
  int qt = swz & 7, bh = swz >> 3;
  int b = bh >> 5, h = bh & 31, g = h >> 2;
  int tid = threadIdx.x, lane = tid & 63, w = tid >> 6;
  int l15 = lane & 15, l4 = lane >> 4;
  size_t rowbase = (size_t)b * 2048;

  // Q fragments hoisted to registers: [q=l15][d=ks*32+l4*8]
  bf16x8 aq[4][2];
#pragma unroll
  for (int qf = 0; qf < 4; ++qf)
#pragma unroll
    for (int ks = 0; ks < 2; ++ks)
      aq[qf][ks] = *reinterpret_cast<const bf16x8*>(
          qkv + (rowbase + qt * 256 + w * 64 + qf * 16 + l15) * 2560 + h * 64 + ks * 32 + l4 * 8);

  // staging: chunk c = w*2+j covers rows c*8..c*8+7; LDS slot i&7 holds global slot (i&7)^(r&7)
  int src_r = lane >> 3;
  int sslot = ((lane & 7) ^ src_r) * 8;
  const u16* Kg = qkv + rowbase * 2560 + 2048 + g * 64;
  const u16* Vg = vTg + ((size_t)((b * 8 + g) * 64)) * 2048;

  auto stageKV = [&](int kt, int buf) {
#pragma unroll
    for (int j = 0; j < 2; ++j) {
      int c = w * 2 + j;
      async_cp16(Kg + (size_t)(kt * 64 + c * 8 + src_r) * 2560 + sslot, &Kl[buf][c * 512]);
    }
#pragma unroll
    for (int j = 0; j < 2; ++j) {
      int c = w * 2 + j;
      async_cp16(Vg + (size_t)(c * 8 + src_r) * 2048 + kt * 64 + sslot, &Vl[buf][c * 512]);
    }
  };

  f32x4 oacc[4][4] = {};
  f32x4 lacc[4] = {};
  union { short s[8]; bf16x8 v; } ones;
#pragma unroll
  for (int i = 0; i < 8; ++i) ones.s[i] = 0x3F80;  // bf16 1.0

  stageKV(0, 0);
  const float CEXP = 0.18033688011112042f;  // log2(e)/sqrt(64)
  char* pwb = (char*)&Pw[w][0];

  for (int kt = 0; kt < 32; ++kt) {
    int cur = kt & 1;
    __syncthreads();  // drains stage(kt) [vmcnt] + all waves done reading buf cur^1
    if (kt + 1 < 32) stageKV(kt + 1, cur ^ 1);

    // K fragments for this tile, held across the qf loop
    bf16x8 bk[2][4];
#pragma unroll
    for (int ks = 0; ks < 2; ++ks)
#pragma unroll
      for (int kf = 0; kf < 4; ++kf) {
        int key = kf * 16 + l15;
        bk[ks][kf] = *reinterpret_cast<const bf16x8*>(
            &Kl[cur][key * 64 + (((ks * 4 + l4) ^ (key & 7)) * 8)]);
      }

    // S^T = K Q^T per 16-q group; exp2; pack to Pw (4x b64 per qf, ~4-way banks)
#pragma unroll
    for (int qf = 0; qf < 4; ++qf) {
      f32x4 sq[4] = {};
#pragma unroll
      for (int ks = 0; ks < 2; ++ks)
#pragma unroll
        for (int kf = 0; kf < 4; ++kf)
          sq[kf] = MFMA16(bk[ks][kf], aq[qf][ks], sq[kf]);
      int ql = qf * 16 + l15, rswz = (ql & 7) << 4;
#pragma unroll
      for (int kf = 0; kf < 4; ++kf) {
        union { ushort4 u; __bf16 bb[4]; } pk;
#pragma unroll
        for (int e = 0; e < 4; ++e)
          pk.bb[e] = (__bf16)__builtin_amdgcn_exp2f(sq[kf][e] * CEXP);
        *reinterpret_cast<ushort4*>(pwb + ((ql * 128 + kf * 32 + l4 * 8) ^ rswz)) = pk.u;
      }
    }
    asm volatile("" ::: "memory");  // order P writes before P reads (wave-internal)

    // O += P V ; l += P * ones (rowsum via MFMA)
#pragma unroll
    for (int kc = 0; kc < 2; ++kc) {
      bf16x8 bv[4];
#pragma unroll
      for (int df = 0; df < 4; ++df) {
        int d = df * 16 + l15;
        bv[df] = *reinterpret_cast<const bf16x8*>(
            &Vl[cur][d * 64 + (((kc * 4 + l4) ^ (d & 7)) * 8)]);
      }
#pragma unroll
      for (int qf = 0; qf < 4; ++qf) {
        int ql = qf * 16 + l15;
        bf16x8 pa = *reinterpret_cast<const bf16x8*>(
            pwb + ((ql * 128 + kc * 64 + l4 * 16) ^ ((ql & 7) << 4)));
        lacc[qf] = MFMA16(pa, ones.v, lacc[qf]);
#pragma unroll
        for (int df = 0; df < 4; ++df)
          oacc[qf][df] = MFMA16(pa, bv[df], oacc[qf][df]);
      }
    }
  }

#pragma unroll
  for (int qf = 0; qf < 4; ++qf)
#pragma unroll
    for (int df = 0; df < 4; ++df) {
      int col = h * 64 + df * 16 + l15;
#pragma unroll
      for (int e = 0; e < 4; ++e) {
        size_t row = rowbase + qt * 256 + w * 64 + qf * 16 + l4 * 4 + e;
        attno[row * 2048 + col] = f2bf(oacc[qf][df][e] / lacc[qf][e]);
      }
    }
}

// ---------------- launch ----------------
extern "C" void kernel_launch(void* const* d_in, const int* in_sizes, int n_in,
                              void* d_out, int out_size, void* d_ws, size_t ws_size,
                              hipStream_t stream) {
  const float* x    = (const float*)d_in[0];
  const float* Wqkv = (const float*)d_in[1];
  const float* bqkv = (const float*)d_in[2];
  const float* Wo   = (const float*)d_in[3];
  const float* bo   = (const float*)d_in[4];
  float* out = (float*)d_out;

  char* ws = (char*)d_ws;
  u16* x_bf   = (u16*)(ws);                    // 4096x2048 bf16      (16.8 MB)
  u16* WqkvT  = (u16*)(ws + 16777216);         // 3072x2048           (12.6 MB)
  u16* WoT    = (u16*)(ws + 29360128);         // 2048x2048           ( 8.4 MB)
  u16* qkv_bf = (u16*)(ws + 37748736);         // 4096x2560 (Q|K)     (21.0 MB)
  u16* attno  = (u16*)(ws + 58720256);         // 4096x2048           (16.8 MB)
  u16* vT     = (u16*)(ws + 75497472);         // 16x64x2048 (V^T)    ( 4.2 MB)  end 79.7MB

  cast_bf16_kernel<<<8192, 256, 0, stream>>>(x, x_bf, 2097152);
  transpose_cast_kernel<<<dim3(96, 64), 256, 0, stream>>>(Wqkv, WqkvT, 2048, 3072);
  transpose_cast_kernel<<<dim3(64, 64), 256, 0, stream>>>(Wo, WoT, 2048, 2048);
  gemm_bt_kernel<1><<<384, 512, 0, stream>>>(x_bf, WqkvT, bqkv, qkv_bf, vT,
                                             24, 3072, 2048, 2560);
  attn_kernel<<<512, 256, 0, stream>>>(qkv_bf, vT, attno);
  gemm_bt_kernel<0><<<256, 512, 0, stream>>>(attno, WoT, bo, out, nullptr,
                                             16, 2048, 2048, 2048);
}